// Round 8
// baseline (607.990 us; speedup 1.0000x reference)
//
#include <hip/hip_runtime.h>
#include <stdint.h>

#define B_ 8
#define N_ 4096
#define C_ 512
#define H_ 256
#define NC_ 1000
#define TOTAL_BLOCKS 768

typedef float v4f __attribute__((ext_vector_type(4)));
typedef short v8s __attribute__((ext_vector_type(8)));
typedef unsigned short ushort_t;

__device__ __forceinline__ uint32_t f2bf1(float f) {
    uint32_t u = __float_as_uint(f);
    return (u + 0x7FFFu + ((u >> 16) & 1u)) >> 16;
}
__device__ __forceinline__ uint32_t pk2(float lo, float hi) {
#if __has_builtin(__builtin_amdgcn_cvt_pk_bf16_f32)
    auto r = __builtin_amdgcn_cvt_pk_bf16_f32(lo, hi);   // v_cvt_pk_bf16_f32
    return __builtin_bit_cast(uint32_t, r);
#else
    return f2bf1(lo) | (f2bf1(hi) << 16);
#endif
}

// ---- prep: proj_W -> bf16 B-fragment order; zero pooled + done-counter ------
// NOTE: the row gather (cdist/argmin/inverse-permutation) is algebraically
// dead: the head only consumes the token MEAN, which is permutation-invariant.
// Wfrag (uint4 units): slot[(ntile*16 + kb)*64 + q*16 + c] holds
// bf16(W[ntile*16+c][kb*32 + q*8 + j]), j=0..7.  (exact 524288 B)
__global__ void prep_kernel(const float* __restrict__ W,
                            ushort_t* __restrict__ Wfrag,
                            float* __restrict__ pooled, int* __restrict__ cnt) {
    int blk = blockIdx.x, t = threadIdx.x;
    if (blk == 0) {  // zero pooled (mega accumulates with atomics) + counter
        float4 z = {0.f, 0.f, 0.f, 0.f};
#pragma unroll
        for (int i = 0; i < 4; i++) ((float4*)pooled)[t * 4 + i] = z;
        if (t == 0) *cnt = 0;
    }
    int i = blk * 256 + t;                             // 0..32767 = d*64 + kb*4 + q
    int d = i >> 6, kb = (i >> 2) & 15, q = i & 3;
    const float4* src = (const float4*)(W + d * C_ + kb * 32 + q * 8);
    float4 v0 = src[0], v1 = src[1];
    uint4 pk;
    pk.x = pk2(v0.x, v0.y); pk.y = pk2(v0.z, v0.w);
    pk.z = pk2(v1.x, v1.y); pk.w = pk2(v1.z, v1.w);
    ((uint4*)Wfrag)[((d >> 4) * 16 + kb) * 64 + q * 16 + (d & 15)] = pk;
}

// ---- mega: GEMM+LN+pool blocks (512) + prev-pool blocks (256) + last-block
// MLP head finisher.  One dispatch does everything after prep. ---------------
__global__ __launch_bounds__(512, 4)
void mega_kernel(const float* __restrict__ feat, const float* __restrict__ prev,
                 const ushort_t* __restrict__ Wfrag,
                 const float* __restrict__ pb, const float* __restrict__ lg,
                 const float* __restrict__ lb, float* __restrict__ pooled,
                 int* __restrict__ cnt,
                 const float* __restrict__ W1, const float* __restrict__ b1,
                 const float* __restrict__ W2, const float* __restrict__ b2,
                 const float* __restrict__ W3, const float* __restrict__ b3,
                 float* __restrict__ out) {
    __shared__ __align__(16) char smem[72192];
    v8s* Abuf = (v8s*)smem;                            // 64 KB, 64 rows x 64 chunks
    float (*RowP)[8][64] = (float(*)[8][64])(smem + 65536);  // 4 KB
    float* RowS = (float*)(smem + 69632);              // 256 B
    float* RowQ = (float*)(smem + 69888);              // 256 B
    float* ColS = (float*)(smem + 70144);              // 2 KB
    __shared__ int lastflag;

    const int bid = blockIdx.x;
    const int t = threadIdx.x;

    if (bid % 3 == 2) {
        // ---- prev-pool role: column sums of a 128-row slab ----
        const int p = bid / 3;                          // 0..255
        const int b = p >> 5;
        const int r0 = (p & 31) << 7;
        const float* psrc = prev + ((size_t)(b * N_ + r0)) * C_ + t;
        float sum = 0.f;
#pragma unroll
        for (int g = 0; g < 8; g++) {
            float a[16];
#pragma unroll
            for (int j = 0; j < 16; j++) a[j] = psrc[(g * 16 + j) * C_];
            float s = 0.f;
#pragma unroll
            for (int j = 0; j < 16; j++) s += a[j];
            sum += s;
        }
        atomicAdd(&pooled[b * C_ + t], sum);
    } else {
        // ---- gemm role: 64 sequential rows x 512 cols ----
        const int gix = (bid / 3) * 2 + (bid % 3);      // 0..511
        const int b = gix >> 6;
        const int row0 = (gix & 63) << 6;
        const int wv = t >> 6, lane = t & 63, c = lane & 15, q = lane >> 4;

        // phase 1: stage full A tile; 16 loads in flight, then pack+write
        const int arow = t >> 3;
        const int acol8 = t & 7;
        const float4* s4 = (const float4*)(feat + ((size_t)(b * N_ + row0 + arow) * C_));
        float4 e[8], o[8];
#pragma unroll
        for (int s = 0; s < 8; s++) {
            const int ch = s * 8 + acol8;
            e[s] = s4[ch * 2];
            o[s] = s4[ch * 2 + 1];
        }
#pragma unroll
        for (int s = 0; s < 8; s++) {
            const int ch = s * 8 + acol8;
            uint4 pk;
            pk.x = pk2(e[s].x, e[s].y); pk.y = pk2(e[s].z, e[s].w);
            pk.z = pk2(o[s].x, o[s].y); pk.w = pk2(o[s].z, o[s].w);
            ((uint4*)Abuf)[arow * 64 + (ch ^ (arow & 7))] = pk;
        }

        const ushort_t* fb[4];
#pragma unroll
        for (int nt = 0; nt < 4; nt++)
            fb[nt] = Wfrag + (wv * 4 + nt) * 8192 + lane * 8;

        v4f acc[4][4];
        const v4f vzero = {0.f, 0.f, 0.f, 0.f};
#pragma unroll
        for (int mt = 0; mt < 4; mt++)
#pragma unroll
            for (int nt = 0; nt < 4; nt++) acc[mt][nt] = vzero;

        __syncthreads();

        // phase 2: barrier-free K loop (only L2-hit B loads in vm queue)
#pragma unroll 2
        for (int kb = 0; kb < 16; kb++) {
            v8s af[4], bf[4];
#pragma unroll
            for (int nt = 0; nt < 4; nt++)
                bf[nt] = *((const v8s*)(fb[nt] + kb * 512));
#pragma unroll
            for (int mt = 0; mt < 4; mt++)
                af[mt] = Abuf[(mt * 16 + c) * 64 + ((kb * 4 + q) ^ (c & 7))];
#pragma unroll
            for (int mt = 0; mt < 4; mt++)
#pragma unroll
                for (int nt = 0; nt < 4; nt++)
                    acc[mt][nt] = __builtin_amdgcn_mfma_f32_16x16x32_bf16(
                        af[mt], bf[nt], acc[mt][nt], 0, 0, 0);
        }

        // epilogue: bias, LN row stats (no LDS atomics), normalize, pool
        float pb4[4], lg4[4], lb4[4];
#pragma unroll
        for (int nt = 0; nt < 4; nt++) {
            int n = wv * 64 + nt * 16 + c;
            pb4[nt] = pb[n]; lg4[nt] = lg[n]; lb4[nt] = lb[n];
        }
#pragma unroll
        for (int mt = 0; mt < 4; mt++) {
#pragma unroll
            for (int reg = 0; reg < 4; reg++) {
                float s1 = 0.f, s2 = 0.f;
#pragma unroll
                for (int nt = 0; nt < 4; nt++) {
                    float v = acc[mt][nt][reg] + pb4[nt];
                    acc[mt][nt][reg] = v;
                    s1 += v; s2 += v * v;
                }
#pragma unroll
                for (int d = 1; d < 16; d <<= 1) {
                    s1 += __shfl_xor(s1, d);
                    s2 += __shfl_xor(s2, d);
                }
                if (c == 0) {
                    int r = mt * 16 + q * 4 + reg;
                    (*RowP)[wv][r] = s1;
                    RowP[1][wv][r] = s2;
                }
            }
        }
        __syncthreads();
        if (t < 64) {
            float s1 = 0.f, s2 = 0.f;
#pragma unroll
            for (int w = 0; w < 8; w++) { s1 += RowP[0][w][t]; s2 += RowP[1][w][t]; }
            float mu = s1 * (1.f / C_);
            float var = s2 * (1.f / C_) - mu * mu;
            RowS[t] = mu;
            RowQ[t] = rsqrtf(var + 1e-5f);
        }
        __syncthreads();
        float col[4] = {0.f, 0.f, 0.f, 0.f};
#pragma unroll
        for (int mt = 0; mt < 4; mt++) {
#pragma unroll
            for (int reg = 0; reg < 4; reg++) {
                int r = mt * 16 + q * 4 + reg;
                float mu = RowS[r], rs = RowQ[r];
#pragma unroll
                for (int nt = 0; nt < 4; nt++)
                    col[nt] += (acc[mt][nt][reg] - mu) * rs * lg4[nt] + lb4[nt];
            }
        }
#pragma unroll
        for (int nt = 0; nt < 4; nt++) {
            col[nt] += __shfl_xor(col[nt], 16);
            col[nt] += __shfl_xor(col[nt], 32);
        }
        if (lane < 16) {
#pragma unroll
            for (int nt = 0; nt < 4; nt++) ColS[wv * 64 + nt * 16 + c] = col[nt];
        }
        __syncthreads();
        atomicAdd(&pooled[b * C_ + t], ColS[t]);
    }

    // ---- finisher: last block to arrive runs the 3-layer MLP head ----
    __syncthreads();
    if (t == 0) {
        __threadfence();
        lastflag = (atomicAdd(cnt, 1) == TOTAL_BLOCKS - 1) ? 1 : 0;
    }
    __syncthreads();
    if (!lastflag) return;
    __threadfence();

    float* P  = (float*)smem;                          // [8][512] = 16 KB
    float* H1 = (float*)(smem + 16384);                // [8][256] =  8 KB
    float* H2 = (float*)(smem + 24576);                // [8][256] =  8 KB

    // coherent read of pooled (atomic RMW +0 -> L2-coherent), apply 1/N
    for (int i = t; i < B_ * C_; i += 512)
        P[i] = atomicAdd(&pooled[i], 0.0f) * (1.f / 4096.f);
    __syncthreads();

    // layer 1: 2048 dots of 512
#pragma unroll
    for (int k = 0; k < 4; k++) {
        const int idx = k * 512 + t;                   // b = idx>>8, j = idx&255
        const int bb = idx >> 8, j = idx & 255;
        const float4* wr = (const float4*)(W1 + j * C_);
        const float4* pp = (const float4*)(P + bb * C_);
        float s = 0.f;
#pragma unroll 8
        for (int kk = 0; kk < 128; kk++) {
            float4 w = wr[kk], p = pp[kk];
            s += w.x * p.x + w.y * p.y + w.z * p.z + w.w * p.w;
        }
        H1[idx] = fmaxf(s + b1[j], 0.f);
    }
    __syncthreads();

    // layer 2: 2048 dots of 256
#pragma unroll
    for (int k = 0; k < 4; k++) {
        const int idx = k * 512 + t;
        const int bb = idx >> 8, j = idx & 255;
        const float4* wr = (const float4*)(W2 + j * H_);
        const float4* pp = (const float4*)(H1 + bb * H_);
        float s = 0.f;
#pragma unroll 8
        for (int kk = 0; kk < 64; kk++) {
            float4 w = wr[kk], p = pp[kk];
            s += w.x * p.x + w.y * p.y + w.z * p.z + w.w * p.w;
        }
        H2[idx] = fmaxf(s + b2[j], 0.f);
    }
    __syncthreads();

    // layer 3: 8000 dots of 256
    for (int i = t; i < B_ * NC_; i += 512) {
        const int bb = i / NC_, oo = i - bb * NC_;
        const float4* wr = (const float4*)(W3 + oo * H_);
        const float4* pp = (const float4*)(H2 + bb * H_);
        float s = 0.f;
#pragma unroll 8
        for (int kk = 0; kk < 64; kk++) {
            float4 w = wr[kk], p = pp[kk];
            s += w.x * p.x + w.y * p.y + w.z * p.z + w.w * p.w;
        }
        out[i] = s + b3[oo];
    }
}

extern "C" void kernel_launch(void* const* d_in, const int* in_sizes, int n_in,
                              void* d_out, int out_size, void* d_ws, size_t ws_size,
                              hipStream_t stream) {
    const float* feat  = (const float*)d_in[0];
    const float* prev  = (const float*)d_in[1];
    // d_in[2] = pos_org, d_in[3] = pos_shuffled — unused: the head consumes
    // only the token mean, which is invariant to the row permutation.
    const float* projW = (const float*)d_in[4];
    const float* pb    = (const float*)d_in[5];
    const float* lg    = (const float*)d_in[6];
    const float* lb    = (const float*)d_in[7];
    const float* W1    = (const float*)d_in[8];
    const float* b1    = (const float*)d_in[9];
    const float* W2    = (const float*)d_in[10];
    const float* b2    = (const float*)d_in[11];
    const float* W3    = (const float*)d_in[12];
    const float* b3    = (const float*)d_in[13];
    float* out = (float*)d_out;

    char* ws = (char*)d_ws;
    ushort_t* Wfrag = (ushort_t*)ws;                     // 524288 B (exact)
    float* pooled   = (float*)(ws + 524288);             // 16384 B
    int* cnt        = (int*)(ws + 540672);               // 4 B

    prep_kernel<<<128, 256, 0, stream>>>(projW, Wfrag, pooled, cnt);
    mega_kernel<<<TOTAL_BLOCKS, 512, 0, stream>>>(feat, prev, Wfrag,
                                                  pb, lg, lb, pooled, cnt,
                                                  W1, b1, W2, b2, W3, b3, out);
}